// Round 8
// baseline (45.020 us; speedup 1.0000x reference)
//
#include <hip/hip_runtime.h>
#include <stdint.h>

// (N,T,F)=(128,8192,8), WS=16, E=256 -> nw=512, keep=205, mask=307
#define NB     128
#define TLEN   8192
#define FD     8
#define KD     128          // WS*F (GEMM K)
#define NWIN   512
#define ED     256
#define NKEEP  205
#define NMASK  307

// float32-element offsets in the concatenated output tuple
#define OFF_VIS  0UL
#define OFF_TGT  6717440UL        // + 128*205*256
#define OFF_MSK  16777216UL       // + 128*307*256
#define OFF_VIDX 26836992UL       // + 128*307*256
#define OFF_MIDX 26863232UL       // + 128*205

#define NTILES  4     // MFMA tiles (of 16 slots) per block
#define SLOTS   64    // slots per block
#define ASTRIDE 136   // ushort per A-tile row (128 + 8 pad)

typedef __attribute__((ext_vector_type(8))) short bf16x8;
typedef __attribute__((ext_vector_type(4))) float f32x4;
typedef __attribute__((ext_vector_type(4))) unsigned int u32x4;

static __device__ __forceinline__ unsigned short f2bf(float x) {
  union { float f; unsigned int u; } v; v.f = x;
  unsigned int r = v.u + 0x7fffu + ((v.u >> 16) & 1u);   // RNE
  return (unsigned short)(r >> 16);
}
static __device__ __forceinline__ unsigned int pack2(float a, float b) {
  return (unsigned int)f2bf(a) | ((unsigned int)f2bf(b) << 16);
}

// lgkm-only barrier: LDS ordering without draining global stores
// (__syncthreads would force s_waitcnt vmcnt(0), putting store retirement
// on the critical path every tile).
static __device__ __forceinline__ void lds_barrier() {
  __asm__ volatile("s_waitcnt lgkmcnt(0)" ::: "memory");
  __builtin_amdgcn_s_barrier();
}

// Fully fused TimeMAE preprocessing. Block = 256 thr (4 waves), 64 slots
// (4 MFMA tiles), A staged bf16 in LDS (double-buffered, 2-tile lookahead),
// W frags in registers. MFMA computes D = W_tile x A_tile so D-col = slot,
// D-row = feature: each lane owns slot l15 with 4 consecutive features per
// acc reg -> direct f32x4 stores, no LDS transpose epilogue.
__global__ __launch_bounds__(256) void fused_kernel(
    const float* __restrict__ temps, const float* __restrict__ W,
    const float* __restrict__ b, const float* __restrict__ mask_token,
    const float* __restrict__ pos, const int* __restrict__ perm,
    float* __restrict__ out)
{
  __shared__ __align__(16) unsigned short Abuf[2][16][ASTRIDE];
  __shared__ int Pbuf[SLOTS];

  const int tid  = threadIdx.x;
  const int lane = tid & 63;
  const int wv   = tid >> 6;     // 0..3
  const int l15  = lane & 15;
  const int lhi  = lane >> 4;    // 0..3

  const int n  = blockIdx.x >> 3;         // 8 blocks per batch row
  const int s0 = (blockIdx.x & 7) * SLOTS;
  const int e0 = wv * 64;

  // per-block perm slice -> LDS
  if (tid < SLOTS) Pbuf[tid] = perm[n * NWIN + s0 + tid] & (NWIN - 1);

  // W fragments (a-operand: lane l15 = feature row e0+j*16+l15, elem -> k)
  bf16x8 wb[4][4];
  #pragma unroll
  for (int j = 0; j < 4; ++j) {
    const float* wrow = W + (size_t)(e0 + j * 16 + l15) * KD + lhi * 8;
    #pragma unroll
    for (int kk = 0; kk < 4; ++kk) {
      f32x4 w0 = *(const f32x4*)(wrow + kk * 32);
      f32x4 w1 = *(const f32x4*)(wrow + kk * 32 + 4);
      bf16x8 f;
      f[0] = (short)f2bf(w0[0]); f[1] = (short)f2bf(w0[1]);
      f[2] = (short)f2bf(w0[2]); f[3] = (short)f2bf(w0[3]);
      f[4] = (short)f2bf(w1[0]); f[5] = (short)f2bf(w1[1]);
      f[6] = (short)f2bf(w1[2]); f[7] = (short)f2bf(w1[3]);
      wb[j][kk] = f;
    }
  }
  // bias / mask_token fragments in D layout: feature = e0 + j*16 + lhi*4 + r
  f32x4 bb4[4], mm4[4];
  #pragma unroll
  for (int j = 0; j < 4; ++j) {
    bb4[j] = *(const f32x4*)&b[e0 + j * 16 + lhi * 4];
    mm4[j] = *(const f32x4*)&mask_token[e0 + j * 16 + lhi * 4];
  }

  const float* tbase = temps + (size_t)n * (TLEN * FD);

  // staging roles: thread -> (row 0..15, seg 0..15), 8 floats per thread
  const int srow = tid >> 4;
  const int sseg = tid & 15;

  lds_barrier();   // Pbuf ready

  // stage tile 0 -> Abuf[0]
  {
    const float* src = tbase + (size_t)Pbuf[srow] * KD + sseg * 8;
    f32x4 v0 = *(const f32x4*)src;
    f32x4 v1 = *(const f32x4*)(src + 4);
    u32x4 pk;
    pk[0] = pack2(v0[0], v0[1]); pk[1] = pack2(v0[2], v0[3]);
    pk[2] = pack2(v1[0], v1[1]); pk[3] = pack2(v1[2], v1[3]);
    *(u32x4*)&Abuf[0][srow][sseg * 8] = pk;
  }
  // issue tile-1 loads
  f32x4 q0, q1;
  {
    const float* src = tbase + (size_t)Pbuf[16 + srow] * KD + sseg * 8;
    q0 = *(const f32x4*)src;
    q1 = *(const f32x4*)(src + 4);
  }
  lds_barrier();   // Abuf[0] ready

  const f32x4 zero = {0.f, 0.f, 0.f, 0.f};

  for (int t = 0; t < NTILES; ++t) {
    // ---- compute tile t: acc[j][r] = emb[slot=l15][feat=e0+j*16+lhi*4+r] ----
    f32x4 acc[4];
    acc[0] = zero; acc[1] = zero; acc[2] = zero; acc[3] = zero;
    #pragma unroll
    for (int kk = 0; kk < 4; ++kk) {
      const bf16x8 a = *(const bf16x8*)&Abuf[t & 1][l15][kk * 32 + lhi * 8];
      #pragma unroll
      for (int j = 0; j < 4; ++j)
        acc[j] = __builtin_amdgcn_mfma_f32_16x16x32_bf16(wb[j][kk], a, acc[j], 0, 0, 0);
    }

    // pack lookahead tile t+1 into the other buffer
    if (t + 1 < NTILES) {
      u32x4 pk;
      pk[0] = pack2(q0[0], q0[1]); pk[1] = pack2(q0[2], q0[3]);
      pk[2] = pack2(q1[0], q1[1]); pk[3] = pack2(q1[2], q1[3]);
      *(u32x4*)&Abuf[(t + 1) & 1][srow][sseg * 8] = pk;
    }
    // issue global loads for tile t+2
    if (t + 2 < NTILES) {
      const float* src = tbase + (size_t)Pbuf[(t + 2) * 16 + srow] * KD + sseg * 8;
      q0 = *(const f32x4*)src;
      q1 = *(const f32x4*)(src + 4);
    }

    // ---- epilogue: direct stores (no LDS transpose) ----
    {
      const int slot = s0 + t * 16 + l15;
      const int wr   = Pbuf[t * 16 + l15];
      const bool vis = slot < NKEEP;
      const size_t rowb = vis
          ? OFF_VIS + (size_t)(n * NKEEP + slot) * ED
          : OFF_TGT + (size_t)(n * NMASK + (slot - NKEEP)) * ED;
      const size_t mskb = OFF_MSK + (size_t)(n * NMASK + (slot - NKEEP)) * ED;
      const float* prow = pos + (size_t)wr * ED + e0 + lhi * 4;
      #pragma unroll
      for (int j = 0; j < 4; ++j) {
        const f32x4 pz = *(const f32x4*)(prow + j * 16);
        *(f32x4*)&out[rowb + (size_t)(e0 + j * 16 + lhi * 4)] = acc[j] + bb4[j] + pz;
        if (!vis)
          *(f32x4*)&out[mskb + (size_t)(e0 + j * 16 + lhi * 4)] = mm4[j] + pz;
      }
      if (wv == 0 && lhi == 0) {
        if (vis) out[OFF_VIDX + (size_t)n * NKEEP + slot] = (float)wr;
        else     out[OFF_MIDX + (size_t)n * NMASK + (slot - NKEEP)] = (float)wr;
      }
    }

    if (t + 1 < NTILES) lds_barrier();   // Abuf handoff (stores keep draining)
  }
}

extern "C" void kernel_launch(void* const* d_in, const int* in_sizes, int n_in,
                              void* d_out, int out_size, void* d_ws, size_t ws_size,
                              hipStream_t stream) {
  // Identify inputs by flat size (sizes distinct except b/mask_token; b first).
  int i_temps = 0, i_W = 1, i_b = 2, i_mt = 3, i_pos = 4, i_perm = 5;
  int small[2] = {-1, -1}; int nsmall = 0;
  for (int i = 0; i < n_in; ++i) {
    const int s = in_sizes[i];
    if (s == NB * TLEN * FD)        i_temps = i;
    else if (s == ED * KD)          i_W = i;
    else if (s == 1024 * ED)        i_pos = i;
    else if (s == NB * NWIN)        i_perm = i;
    else if (s == ED && nsmall < 2) small[nsmall++] = i;
  }
  if (nsmall == 2) { i_b = small[0]; i_mt = small[1]; }

  const float* temps      = (const float*)d_in[i_temps];
  const float* W          = (const float*)d_in[i_W];
  const float* b          = (const float*)d_in[i_b];
  const float* mask_token = (const float*)d_in[i_mt];
  const float* pos        = (const float*)d_in[i_pos];
  const int*   perm       = (const int*)d_in[i_perm];
  float* out = (float*)d_out;

  fused_kernel<<<dim3(NB * 8), dim3(256), 0, stream>>>(
      temps, W, b, mask_token, pos, perm, out);
}